// Round 2
// 368.254 us; speedup vs baseline: 1.1167x; 1.1167x over previous
//
#include <hip/hip_runtime.h>

// SRLSecondOrderScorer: B=2, N=128, D_IN=1024, D=150. Inputs f32, outputs f32.
// Round 7 (= round 6 resubmit after infra failure): fuse tmp_gemm+s_gemm (tmp
// tile stays in LDS) and fuse triu_sym into the s epilogue (block-local LDS
// transpose). 6 launches total.
// Chain per group g: TT3g[g][(j*160+i)][k] = bf16(T_g[i][k][j])
//   wz3g[g][bz][j*160+i] = sum_k Z[bz,k]*TT3                     (MFMA GEMM)
//   tmp[x][j]            = sum_i X[b,x,i]*wz3     (in-LDS, fused)
//   s[g][bz][x][y]       = sum_j tmp*Y[b,y,j]     (+ triu_sym for g=1..3,
//                                                  upper-tri only for g=4,5)
// H rows padded to 160 with exact zeros => all K-padding inert.

#define DD    150
#define KP    160
#define OUTBLK 4194304       // 2*128^3 floats
#define NWZ   24064          // wz3 row stride (188*128); cols>=24000 written zero
#define TTG   3840000        // shorts per TT3 group (24000 rows x 160)
#define WZG   (256*NWZ)      // shorts per wz3 group
#define HROW  (256*160)      // shorts per H region

__device__ __forceinline__ unsigned short f2u(float f) {  // RNE f32->bf16
  unsigned x = __float_as_uint(f);
  x += 0x7FFFu + ((x >> 16) & 1u);
  return (unsigned short)(x >> 16);
}

typedef __attribute__((ext_vector_type(8))) short frag8;
typedef __attribute__((ext_vector_type(4))) float facc4;

__constant__ int c_zsel[6] = {2, 2, 2, 2, 0, 1};  // Z region per group (sh,st,pp = 0,1,2)
__constant__ int c_xsel[6] = {0, 0, 0, 1, 2, 2};
__constant__ int c_ysel[6] = {1, 1, 0, 1, 2, 2};

// ---------------- MLP split-K partials: P[m][ks][bn][160] ----------------
__global__ __launch_bounds__(256) void mlp_partial(
    const float* __restrict__ x,
    const float* __restrict__ W0, const float* __restrict__ W1, const float* __restrict__ W2,
    float* __restrict__ P)
{
  int m = blockIdx.x, bt = blockIdx.y, ks = blockIdx.z;
  const float* W = (m == 0) ? W0 : (m == 1) ? W1 : W2;
  int bn0 = bt * 32, k0 = ks * 128;
  __shared__ float xs[32][132];
  int tid = threadIdx.x;
  for (int e = 0; e < 4; ++e) {
    int l = e * 256 + tid;
    int row = l >> 5, c4 = l & 31;
    float4 v = *(const float4*)&x[(bn0 + row) * 1024 + k0 + c4 * 4];
    xs[row][c4 * 4 + 0] = v.x; xs[row][c4 * 4 + 1] = v.y;
    xs[row][c4 * 4 + 2] = v.z; xs[row][c4 * 4 + 3] = v.w;
  }
  __syncthreads();
  int tj = tid & 15, tt = tid >> 4, r = tt * 2;
  int dd[10];
  #pragma unroll
  for (int u = 0; u < 10; ++u) { int d = tj + 16 * u; dd[u] = d < 150 ? d : 149; }
  float a0[10], a1[10];
  #pragma unroll
  for (int u = 0; u < 10; ++u) { a0[u] = 0.f; a1[u] = 0.f; }
  for (int k = 0; k < 128; ++k) {
    float xa = xs[r][k], xb = xs[r + 1][k];
    const float* wr = W + (long long)(k0 + k) * 150;
    #pragma unroll
    for (int u = 0; u < 10; ++u) {
      float w = wr[dd[u]];
      a0[u] += xa * w; a1[u] += xb * w;
    }
  }
  float* Pb = P + (long long)(m * 8 + ks) * 256 * 160;
  #pragma unroll
  for (int u = 0; u < 10; ++u) {
    int d = tj + 16 * u;
    Pb[(bn0 + r) * 160 + d]     = a0[u];
    Pb[(bn0 + r + 1) * 160 + d] = a1[u];
  }
}

// ---------------- MLP reduce: H[m][bn][160] bf16 (pads exact zero) ----------------
__global__ __launch_bounds__(256) void mlp_reduce(
    const float* __restrict__ P,
    const float* __restrict__ B0, const float* __restrict__ B1, const float* __restrict__ B2,
    unsigned short* __restrict__ H)
{
  int o = blockIdx.x * 256 + threadIdx.x;     // < 3*256*160
  int d = o % 160;
  int bn = (o / 160) & 255;
  int m = o / (160 * 256);
  float v = 0.f;
  if (d < 150) {
    const float* Bv = (m == 0) ? B0 : (m == 1) ? B1 : B2;
    v = Bv[d];
    #pragma unroll
    for (int ks = 0; ks < 8; ++ks)
      v += P[((long long)(m * 8 + ks) * 256 + bn) * 160 + d];
    v = v > 0.f ? v : 0.1f * v;
  }
  H[o] = f2u(v);
}

// ------ TT3g[g][(j*160+i)][k] = bf16(T_g[i][k][j]); i,k pads zero; all 6 groups ------
struct TPtrs { const float* t[6]; };
__global__ __launch_bounds__(256) void tt_kernel(TPtrs tp, unsigned short* __restrict__ TT3)
{
  int i = blockIdx.x;                  // 0..159
  int ky = blockIdx.y % 5, jy = blockIdx.y / 5;
  int k0 = ky * 32, j0 = jy * 32;
  int g = blockIdx.z;
  const float* T = tp.t[g];
  unsigned short* TT = TT3 + (long long)g * TTG;
  __shared__ float tl[32][33];
  int tid = threadIdx.x;
  #pragma unroll
  for (int e = 0; e < 4; ++e) {
    int l = e * 256 + tid;
    int r = l >> 5, c = l & 31;
    float v = 0.f;
    if (i < 150 && k0 + r < 150 && j0 + c < 150)
      v = T[i * 22500 + (k0 + r) * 150 + (j0 + c)];
    tl[r][c] = v;
  }
  __syncthreads();
  #pragma unroll
  for (int e = 0; e < 4; ++e) {
    int l = e * 256 + tid;
    int rr = l >> 5, cc = l & 31;
    if (j0 + rr < 150)
      TT[(long long)((j0 + rr) * 160 + i) * 160 + k0 + cc] = f2u(tl[cc][rr]);
  }
}

// ---- wz3g[g][m][n] = sum_k Z_g[m,k]*TT3g[g][n][k]; grid (188, 2, 6), bf16 out ----
__global__ __launch_bounds__(256) void wz_gemm(
    const unsigned short* __restrict__ Hb, const unsigned short* __restrict__ TT3,
    unsigned short* __restrict__ wz3)
{
  constexpr int LR = 72;
  __shared__ unsigned short lA[128 * LR];
  __shared__ unsigned short lB[128 * LR];
  int g = blockIdx.z, tid = threadIdx.x;
  const unsigned short* Ab = Hb + c_zsel[g] * HROW + blockIdx.y * 128 * 160;
  const unsigned short* Bb = TT3 + (long long)g * TTG;
  int n0 = blockIdx.x * 128;
  int wave = tid >> 6, lane = tid & 63;
  int l15 = lane & 15, lq = lane >> 4;
  int mw = (wave & 1) * 64, nw = (wave >> 1) * 64;
  facc4 acc[4][4];
  #pragma unroll
  for (int i = 0; i < 4; ++i)
    #pragma unroll
    for (int j = 0; j < 4; ++j) acc[i][j] = (facc4){0.f, 0.f, 0.f, 0.f};
  for (int ch = 0; ch < 3; ++ch) {
    int k0 = ch << 6;
    int sh = (ch == 2) ? 2 : 3, upr = 1 << sh;
    for (int u = tid; u < 128 * upr; u += 256) {
      int row = u >> sh, off = (u & (upr - 1)) << 3;
      *(uint4*)&lA[row * LR + off] = *(const uint4*)&Ab[row * 160 + k0 + off];
    }
    for (int u = tid; u < 128 * upr; u += 256) {
      int row = u >> sh, off = (u & (upr - 1)) << 3;
      int gn = n0 + row;
      uint4 v; v.x = 0u; v.y = 0u; v.z = 0u; v.w = 0u;
      if (gn < 24000) v = *(const uint4*)&Bb[(long long)gn * 160 + k0 + off];
      *(uint4*)&lB[row * LR + off] = v;
    }
    __syncthreads();
    int nks = (ch == 2) ? 1 : 2;
    for (int ks = 0; ks < nks; ++ks) {
      int ko = (ks << 5) + (lq << 3);
      frag8 af[4], bfr[4];
      #pragma unroll
      for (int i = 0; i < 4; ++i) af[i] = *(const frag8*)&lA[(mw + i * 16 + l15) * LR + ko];
      #pragma unroll
      for (int j = 0; j < 4; ++j) bfr[j] = *(const frag8*)&lB[(nw + j * 16 + l15) * LR + ko];
      #pragma unroll
      for (int i = 0; i < 4; ++i)
        #pragma unroll
        for (int j = 0; j < 4; ++j)
          acc[i][j] = __builtin_amdgcn_mfma_f32_16x16x32_bf16(af[i], bfr[j], acc[i][j], 0, 0, 0);
    }
    __syncthreads();
  }
  unsigned short* C = wz3 + (long long)g * WZG;
  int mb = blockIdx.y * 128 + mw;
  #pragma unroll
  for (int i = 0; i < 4; ++i)
    #pragma unroll
    for (int r = 0; r < 4; ++r) {
      int m = mb + i * 16 + lq * 4 + r;
      #pragma unroll
      for (int j = 0; j < 4; ++j)
        C[(long long)m * NWZ + n0 + nw + j * 16 + l15] = f2u(acc[i][j][r]);
    }
}

// ---- fused tmp+s per z: tmp[x][j]=sum_i X[x,i]*wz3 (kept in LDS, bf16),
//      then s[x][y]=sum_j tmp*Y[y,j]; sym fused in epilogue. grid (1536) ----
struct SPtrs { float* p[6]; };
__global__ __launch_bounds__(256) void tmps_gemm(
    const unsigned short* __restrict__ Hb, const unsigned short* __restrict__ wz3,
    SPtrs sp)
{
  // LDS phases (union, 64 KB): p1 = staging for tmp GEMM; p2 = tmp tile (bf16,
  // row stride 168 => 2-way-free bank pattern) + Y staging; sq = f32 sym tile
  // (col XOR-swizzled so transposed reads don't 16-way conflict).
  __shared__ union {
    struct { unsigned short A[128 * 72]; unsigned short B[160 * 72]; } p1;
    struct { unsigned short T[128 * 168]; unsigned short B[128 * 72]; } p2;
    float sq[128 * 128];
  } sm;

  int z = blockIdx.x, tid = threadIdx.x;
  int g = z >> 8, bz = z & 255, b = bz >> 7;
  const unsigned short* Ab = Hb + c_xsel[g] * HROW + b * 128 * 160;
  const unsigned short* Bb = wz3 + (long long)g * WZG + (long long)bz * NWZ;
  int wave = tid >> 6, lane = tid & 63;
  int l15 = lane & 15, lq = lane >> 4;
  int mw = (wave & 1) * 64;
  int nw80 = (wave >> 1) * 80, nw64 = (wave >> 1) * 64;

  // ---------- phase 1: tmp[x 128][j 160] = X[128x160] * wz[150x160 pad]^T ----------
  facc4 acc[4][5];
  #pragma unroll
  for (int i = 0; i < 4; ++i)
    #pragma unroll
    for (int j = 0; j < 5; ++j) acc[i][j] = (facc4){0.f, 0.f, 0.f, 0.f};
  for (int ch = 0; ch < 3; ++ch) {
    int k0 = ch << 6;
    int sh = (ch == 2) ? 2 : 3, upr = 1 << sh;
    for (int u = tid; u < 128 * upr; u += 256) {
      int row = u >> sh, off = (u & (upr - 1)) << 3;
      *(uint4*)&sm.p1.A[row * 72 + off] = *(const uint4*)&Ab[row * 160 + k0 + off];
    }
    for (int u = tid; u < 160 * upr; u += 256) {
      int row = u >> sh, off = (u & (upr - 1)) << 3;
      uint4 v; v.x = 0u; v.y = 0u; v.z = 0u; v.w = 0u;
      if (row < 150) v = *(const uint4*)&Bb[row * 160 + k0 + off];
      *(uint4*)&sm.p1.B[row * 72 + off] = v;
    }
    __syncthreads();
    int nks = (ch == 2) ? 1 : 2;
    for (int ks = 0; ks < nks; ++ks) {
      int ko = (ks << 5) + (lq << 3);
      frag8 af[4], bfr[5];
      #pragma unroll
      for (int i = 0; i < 4; ++i) af[i] = *(const frag8*)&sm.p1.A[(mw + i * 16 + l15) * 72 + ko];
      #pragma unroll
      for (int j = 0; j < 5; ++j) bfr[j] = *(const frag8*)&sm.p1.B[(nw80 + j * 16 + l15) * 72 + ko];
      #pragma unroll
      for (int i = 0; i < 4; ++i)
        #pragma unroll
        for (int j = 0; j < 5; ++j)
          acc[i][j] = __builtin_amdgcn_mfma_f32_16x16x32_bf16(af[i], bfr[j], acc[i][j], 0, 0, 0);
    }
    __syncthreads();
  }

  // ---------- tmp (bf16) -> LDS; each wave writes its own (mw, nw80) quadrant ----------
  #pragma unroll
  for (int i = 0; i < 4; ++i)
    #pragma unroll
    for (int r = 0; r < 4; ++r) {
      int m = mw + i * 16 + lq * 4 + r;
      #pragma unroll
      for (int j = 0; j < 5; ++j)
        sm.p2.T[m * 168 + nw80 + j * 16 + l15] = f2u(acc[i][j][r]);
    }

  // ---------- phase 2: s[x 128][y 128] = tmp[128x160] * Y[128x160]^T ----------
  const unsigned short* Yb = Hb + c_ysel[g] * HROW + b * 128 * 160;
  facc4 acc2[4][4];
  #pragma unroll
  for (int i = 0; i < 4; ++i)
    #pragma unroll
    for (int j = 0; j < 4; ++j) acc2[i][j] = (facc4){0.f, 0.f, 0.f, 0.f};
  for (int ch = 0; ch < 3; ++ch) {
    int k0 = ch << 6;
    int sh = (ch == 2) ? 2 : 3, upr = 1 << sh;
    __syncthreads();    // ch0: T writes visible; ch1/2: prev frag reads of p2.B done
    for (int u = tid; u < 128 * upr; u += 256) {
      int row = u >> sh, off = (u & (upr - 1)) << 3;
      *(uint4*)&sm.p2.B[row * 72 + off] = *(const uint4*)&Yb[row * 160 + k0 + off];
    }
    __syncthreads();
    int nks = (ch == 2) ? 1 : 2;
    for (int ks = 0; ks < nks; ++ks) {
      int ko = (ks << 5) + (lq << 3);
      frag8 af[4], bfr[4];
      #pragma unroll
      for (int i = 0; i < 4; ++i)
        af[i] = *(const frag8*)&sm.p2.T[(mw + i * 16 + l15) * 168 + k0 + ko];
      #pragma unroll
      for (int j = 0; j < 4; ++j)
        bfr[j] = *(const frag8*)&sm.p2.B[(nw64 + j * 16 + l15) * 72 + ko];
      #pragma unroll
      for (int i = 0; i < 4; ++i)
        #pragma unroll
        for (int j = 0; j < 4; ++j)
          acc2[i][j] = __builtin_amdgcn_mfma_f32_16x16x32_bf16(af[i], bfr[j], acc2[i][j], 0, 0, 0);
    }
  }

  // ---------- epilogue ----------
  float* C = sp.p[g] + (long long)bz * 16384;
  if (g >= 1 && g <= 3) {
    // fused triu_sym: out[x,y] = s[min,max]. Block holds the full 128x128 plane.
    __syncthreads();    // all frag reads of p2 done before sq overwrites it
    #pragma unroll
    for (int i = 0; i < 4; ++i)
      #pragma unroll
      for (int r = 0; r < 4; ++r) {
        int m = mw + i * 16 + lq * 4 + r;
        #pragma unroll
        for (int j = 0; j < 4; ++j) {
          int n = nw64 + j * 16 + l15;
          sm.sq[m * 128 + (n ^ (m & 31))] = acc2[i][j][r];
        }
      }
    __syncthreads();
    #pragma unroll
    for (int i = 0; i < 4; ++i)
      #pragma unroll
      for (int r = 0; r < 4; ++r) {
        int m = mw + i * 16 + lq * 4 + r;
        #pragma unroll
        for (int j = 0; j < 4; ++j) {
          int n = nw64 + j * 16 + l15;
          int mn = m < n ? m : n;
          int mx = m ^ n ^ mn;
          C[m * 128 + n] = sm.sq[mn * 128 + (mx ^ (mn & 31))];
        }
      }
  } else if (g == 0) {
    #pragma unroll
    for (int i = 0; i < 4; ++i)
      #pragma unroll
      for (int r = 0; r < 4; ++r) {
        int m = mw + i * 16 + lq * 4 + r;
        #pragma unroll
        for (int j = 0; j < 4; ++j)
          C[m * 128 + nw64 + j * 16 + l15] = acc2[i][j][r];
      }
  } else {
    // cop groups: cop_kernel only reads sx<=sy -> upper triangle only
    #pragma unroll
    for (int i = 0; i < 4; ++i)
      #pragma unroll
      for (int r = 0; r < 4; ++r) {
        int m = mw + i * 16 + lq * 4 + r;
        #pragma unroll
        for (int j = 0; j < 4; ++j) {
          int n = nw64 + j * 16 + l15;
          if (m <= n) C[m * 128 + n] = acc2[i][j][r];
        }
      }
  }
}

// ---------- cop: out[b,x,y,z] = ss[g][b,z,min(x,y),max(x,y)]; grid (512,4,4) ----------
__global__ __launch_bounds__(256) void cop_kernel(
    const float* __restrict__ ss, float* __restrict__ out)
{
  int w0 = blockIdx.x << 5;
  int z0 = blockIdx.y << 5;
  int g  = blockIdx.z >> 1, b = blockIdx.z & 1;
  const float* sg = ss + (long long)g * OUTBLK;
  float* outp = out + (long long)(4 + g) * OUTBLK;
  __shared__ float tl[32][33];
  int tid = threadIdx.x;
  #pragma unroll
  for (int e = 0; e < 4; ++e) {
    int l = e * 256 + tid;
    int r = l >> 5, c = l & 31;
    int w = w0 + c;
    int xx = w >> 7, yy = w & 127;
    int sx = xx < yy ? xx : yy;
    int sy = xx < yy ? yy : xx;
    tl[r][c] = sg[(((b << 7) + z0 + r) << 14) + (sx << 7) + sy];
  }
  __syncthreads();
  #pragma unroll
  for (int e = 0; e < 4; ++e) {
    int l = e * 256 + tid;
    int rr = l >> 5, cc = l & 31;
    outp[(b << 21) + ((w0 + rr) << 7) + z0 + cc] = tl[cc][rr];
  }
}

extern "C" void kernel_launch(void* const* d_in, const int* in_sizes, int n_in,
                              void* d_out, int out_size, void* d_ws, size_t ws_size,
                              hipStream_t stream)
{
  const float* x   = (const float*)d_in[0];
  const float* Wsh = (const float*)d_in[1];
  const float* bsh = (const float*)d_in[2];
  const float* Wst = (const float*)d_in[3];
  const float* bst = (const float*)d_in[4];
  const float* Wp  = (const float*)d_in[5];
  const float* bp  = (const float*)d_in[6];
  TPtrs tp;
  tp.t[0] = (const float*)d_in[8];   // T_ph    (span_psh)
  tp.t[1] = (const float*)d_in[7];   // T_pt    (span_pst)
  tp.t[2] = (const float*)d_in[9];   // T_phsib
  tp.t[3] = (const float*)d_in[10];  // T_ptsib
  tp.t[4] = (const float*)d_in[11];  // T_phcop
  tp.t[5] = (const float*)d_in[12];  // T_ptcop
  float* out = (float*)d_out;
  char* wsb = (char*)d_ws;

  // ws layout (bytes): H 245,760 | TT3g 46,080,000 | wz3g 73,924,608
  // P (7.9MB) aliases wz3g (dead before wz writes); ss (33.6MB) aliases TT3g
  // (TT3 fully consumed by wz_gemm before tmps_gemm writes ss).
  unsigned short* Hb   = (unsigned short*)(wsb);
  unsigned short* TT3  = (unsigned short*)(wsb + 245760);
  unsigned short* wz3  = (unsigned short*)(wsb + 46325760);
  float* P  = (float*)wz3;
  float* ss = (float*)TT3;

  SPtrs sp;
  sp.p[0] = out + 0LL * OUTBLK;
  sp.p[1] = out + 1LL * OUTBLK;
  sp.p[2] = out + 2LL * OUTBLK;
  sp.p[3] = out + 3LL * OUTBLK;
  sp.p[4] = ss;
  sp.p[5] = ss + OUTBLK;

  mlp_partial<<<dim3(3, 8, 8),    256, 0, stream>>>(x, Wsh, Wst, Wp, P);
  mlp_reduce <<<dim3(480),        256, 0, stream>>>(P, bsh, bst, bp, Hb);
  tt_kernel  <<<dim3(160, 25, 6), 256, 0, stream>>>(tp, TT3);
  wz_gemm    <<<dim3(188, 2, 6),  256, 0, stream>>>(Hb, TT3, wz3);
  tmps_gemm  <<<dim3(1536),       256, 0, stream>>>(Hb, wz3, sp);
  cop_kernel <<<dim3(512, 4, 4),  256, 0, stream>>>(ss, out);
}